// Round 7
// baseline (409.506 us; speedup 1.0000x reference)
//
#include <hip/hip_runtime.h>
#include <cstdint>
#include <cstddef>

typedef unsigned short u16;
typedef unsigned int   u32;
typedef __bf16 bf16x8 __attribute__((ext_vector_type(8)));
typedef float  f32x4  __attribute__((ext_vector_type(4)));

#define D_MODEL 1024
#define SEQ     2048
#define NTOK    4096   // B*S
#define NHEAD   16
#define DK      64

// raw sync primitives for counted-vmcnt pipelines (no vmcnt(0) drains in-loop)
#define FENCE() asm volatile("" ::: "memory")
#define SBAR()  asm volatile("s_barrier" ::: "memory")
#define WVL(N)  asm volatile("s_waitcnt vmcnt(" #N ") lgkmcnt(0)" ::: "memory")

// hardware exp2 (v_exp_f32)
__device__ __forceinline__ float fast_exp2(float x) {
  return __builtin_amdgcn_exp2f(x);
}

// fp32 -> bf16 round-to-nearest-even (bit version, for memory-bound kernels)
__device__ __forceinline__ u16 f2bf(float f) {
  u32 u = __builtin_bit_cast(u32, f);
  u += 0x7fffu + ((u >> 16) & 1u);
  return (u16)(u >> 16);
}

// packed fp32x2 -> bf16x2 via compiler casts (lowers to v_cvt_pk_bf16_f32)
__device__ __forceinline__ u32 pkbf(float a, float b) {
  u16 x = __builtin_bit_cast(u16, (__bf16)a);
  u16 y = __builtin_bit_cast(u16, (__bf16)b);
  return (u32)x | ((u32)y << 16);
}

// async global->LDS, 16B per lane (dest must be wave-uniform base + lane*16)
__device__ __forceinline__ void gload16(const u16* g, u16* l) {
  __builtin_amdgcn_global_load_lds(
      (__attribute__((address_space(1))) void*)(uintptr_t)g,
      (__attribute__((address_space(3))) void*)l,
      16, 0, 0);
}

// ---------------------------------------------------------------------------
// Kernel 0: per-batch mask compaction scan.  idx[b][j] = s of j-th live key,
// cnt[b] = #live; idx pads (j>=cnt) = 0.
// ---------------------------------------------------------------------------
__global__ __launch_bounds__(256) void mask_scan(const int* __restrict__ mask,
                                                 int* __restrict__ idx,
                                                 int* __restrict__ cnt) {
  const int b = blockIdx.x, t = threadIdx.x;
  const int lane = t & 63, w = t >> 6;
  __shared__ int sW[4];
  __shared__ int sTot;
  int m8[8];
  const int base = b * SEQ + t * 8;
  int tot = 0;
#pragma unroll
  for (int i = 0; i < 8; ++i) {
    m8[i] = (mask[base + i] != 0);
    tot += m8[i];
  }
  int v = tot;  // wave inclusive scan
#pragma unroll
  for (int d = 1; d < 64; d <<= 1) {
    int u = __shfl_up(v, d);
    if (lane >= d) v += u;
  }
  if (lane == 63) sW[w] = v;
  __syncthreads();
  if (t == 0) {
    int run = 0;
#pragma unroll
    for (int i = 0; i < 4; ++i) { int tmp = sW[i]; sW[i] = run; run += tmp; }
    sTot = run;
  }
  __syncthreads();
  int pos = v - tot + sW[w];  // exclusive prefix for this thread
#pragma unroll
  for (int i = 0; i < 8; ++i)
    if (m8[i]) idx[b * SEQ + pos++] = t * 8 + i;
  const int cn = sTot;
  if (t == 0) cnt[b] = cn;
  for (int j = cn + t; j < SEQ; j += 256) idx[b * SEQ + j] = 0;
}

// ---------------------------------------------------------------------------
// Kernel 1: fp32 -> bf16 conversion for WEIGHTS only (4 x 1M)
// ---------------------------------------------------------------------------
__global__ __launch_bounds__(256) void w_convert(
    const float* __restrict__ wq, const float* __restrict__ wk,
    const float* __restrict__ wv, const float* __restrict__ wo,
    u16* __restrict__ wb) {
  const int total = 1 << 20;  // float4 chunks: 4 * 2^18
  for (int cid = blockIdx.x * blockDim.x + threadIdx.x; cid < total;
       cid += gridDim.x * blockDim.x) {
    int which = cid >> 18;
    int off = cid & ((1 << 18) - 1);
    const float* src = which == 0 ? wq : (which == 1 ? wk : (which == 2 ? wv : wo));
    u16* dst = wb + ((size_t)which << 20);
    float4 f = ((const float4*)src)[off];
    ushort4 u;
    u.x = f2bf(f.x); u.y = f2bf(f.y); u.z = f2bf(f.z); u.w = f2bf(f.w);
    ((ushort4*)dst)[off] = u;
  }
}

// ---------------------------------------------------------------------------
// Kernel 2: QKV projections, fp32 A read directly (conversion fused).
// C[M,N] = A[M,K]*B[N,K]^T + bias, bf16 out.  128x64 tile, BK=64, grid
// (32,16,3) = 1536 blocks = EXACTLY 6/CU (LDS 24KB, launch_bounds(256,6)).
// Round-6 analysis: 128x128 tile at 3 blocks/CU was critical-path x
// interleave bound (22% occupancy, nothing saturated).  Halving tile-N
// doubles independent blocks/CU 3->6; per-step structure unchanged:
//   A: fp32 reg-staged 1-step flight; cvt_pk -> sA (single, 16KB).
//   B: gload16 -> sB single (8KB), issued post-b2, write-window flight.
//   FIFO at top: [A(k+1):8 old, B(k):2 new] -> WVL(0) (both covered).
// Per-row rotated k-slots -> conflict-free ds_read_b128 (wm,wn = 0 mod 8).
// T5 setprio around MFMA clusters (independent-block regime, m191-positive).
// z==0: Q scaled by 0.125*log2(e).  z==2: V transposed [b][h][d][s].
// ---------------------------------------------------------------------------
__global__ __launch_bounds__(256, 6) void gemm_qkv(
    const float* __restrict__ Aq, const float* __restrict__ Ak,
    const float* __restrict__ Av, const u16* __restrict__ Bw,
    const float* __restrict__ b0, const float* __restrict__ b1,
    const float* __restrict__ b2, u16* __restrict__ Cout) {
  __shared__ __align__(16) u16 smem[12288];  // sA[0,8K) sB[8K,12K); epi: sC

  const int t = threadIdx.x;
  const int z = blockIdx.z;
  const float* Ap = (z == 0) ? Aq : ((z == 1) ? Ak : Av);
  const u16* Bp = Bw + ((size_t)z << 20);
  const float* bias = (z == 0) ? b0 : ((z == 1) ? b1 : b2);
  const float scl = (z == 0) ? 0.18033688011f : 1.0f;

  const int m0 = blockIdx.x * 128, n0 = blockIdx.y * 64;
  const int lane = t & 63, wv = t >> 6;
  const int wm = (wv >> 1) * 64, wn = (wv & 1) * 32;
  const int c = lane & 15, qd = lane >> 4;

  // staging: chunk cc = t + 256j -> row = cc>>3, phys slot t&7, source
  // k-slot rotated by row (32j = 0 mod 8 -> j-invariant)
  const int arow = t >> 3;
  const int aoff = (((t & 7) - arow) & 7) * 8;
  const float* gaA = Ap + (size_t)(m0 + arow) * D_MODEL + aoff;
  const u16* gaB = Bp + (size_t)(n0 + arow) * D_MODEL + aoff;

  u16* sA = smem;
  u16* sB = smem + 8192;

  float4 pa[4][2];
  u32 cv[4][4];

  // ---- prologue: A(0):8 -> cvt -> sA; issue A(1):8; issue B(0):2 ----
#pragma unroll
  for (int j = 0; j < 4; ++j) {
    pa[j][0] = *(const float4*)(gaA + (size_t)(32 * j) * D_MODEL);
    pa[j][1] = *(const float4*)(gaA + (size_t)(32 * j) * D_MODEL + 4);
  }
  FENCE();
  WVL(0);  // A(0) regs ready
#pragma unroll
  for (int j = 0; j < 4; ++j) {
    cv[j][0] = pkbf(pa[j][0].x, pa[j][0].y);
    cv[j][1] = pkbf(pa[j][0].z, pa[j][0].w);
    cv[j][2] = pkbf(pa[j][1].x, pa[j][1].y);
    cv[j][3] = pkbf(pa[j][1].z, pa[j][1].w);
  }
  FENCE();
#pragma unroll
  for (int j = 0; j < 4; ++j) {  // issue A(1):8
    pa[j][0] = *(const float4*)(gaA + 64 + (size_t)(32 * j) * D_MODEL);
    pa[j][1] = *(const float4*)(gaA + 64 + (size_t)(32 * j) * D_MODEL + 4);
  }
  FENCE();
#pragma unroll
  for (int j = 0; j < 4; ++j) {
    uint4 v4 = {cv[j][0], cv[j][1], cv[j][2], cv[j][3]};
    *(uint4*)&sA[(t + 256 * j) * 8] = v4;
  }
#pragma unroll
  for (int j = 0; j < 2; ++j)  // issue B(0):2
    gload16(gaB + (size_t)(32 * j) * D_MODEL, sB + (t + 256 * j) * 8);
  FENCE();

  f32x4 acc[4][2] = {};

#pragma unroll
  for (int kbi = 0; kbi < 16; ++kbi) {
    // top: retire [A(kbi+1):8 (1-step flight), B(kbi):2 (write-window flight)]
    // lgkmcnt(0) drains our sA ds_writes before the barrier.
    WVL(0);
    SBAR();  // b1: sA(kbi) + sB(kbi) visible to all waves
#pragma unroll
    for (int s = 0; s < 2; ++s) {
      const int ao = ((s * 4 + qd + wm + c) & 7) * 8;  // rotated k-slot
      const int bo = ((s * 4 + qd + wn + c) & 7) * 8;
      bf16x8 af[4], bfr[2];
#pragma unroll
      for (int i = 0; i < 4; ++i)
        af[i] = *(const bf16x8*)&sA[(wm + i * 16 + c) * 64 + ao];
#pragma unroll
      for (int j = 0; j < 2; ++j)
        bfr[j] = *(const bf16x8*)&sB[(wn + j * 16 + c) * 64 + bo];
      __builtin_amdgcn_s_setprio(1);
#pragma unroll
      for (int i = 0; i < 4; ++i)
#pragma unroll
        for (int j = 0; j < 2; ++j)
          acc[i][j] = __builtin_amdgcn_mfma_f32_16x16x32_bf16(af[i], bfr[j],
                                                              acc[i][j], 0, 0, 0);
      __builtin_amdgcn_s_setprio(0);
    }
    if (kbi + 1 < 16) {
      // cvt A(kbi+1) (regs retired at loop top)
#pragma unroll
      for (int j = 0; j < 4; ++j) {
        cv[j][0] = pkbf(pa[j][0].x, pa[j][0].y);
        cv[j][1] = pkbf(pa[j][0].z, pa[j][0].w);
        cv[j][2] = pkbf(pa[j][1].x, pa[j][1].y);
        cv[j][3] = pkbf(pa[j][1].z, pa[j][1].w);
      }
      if (kbi + 2 < 16) {  // issue A(kbi+2):8 into freed fp32 regs
        const int kb3 = (kbi + 2) * 64;
#pragma unroll
        for (int j = 0; j < 4; ++j) {
          pa[j][0] = *(const float4*)(gaA + kb3 + (size_t)(32 * j) * D_MODEL);
          pa[j][1] = *(const float4*)(gaA + kb3 + (size_t)(32 * j) * D_MODEL + 4);
        }
      }
      FENCE();
      SBAR();  // b2: all waves done reading sA(kbi)/sB(kbi)
      // issue B(kbi+1):2 (flies through the sA-write window + loop latch)
      const int kb2 = (kbi + 1) * 64;
#pragma unroll
      for (int j = 0; j < 2; ++j)
        gload16(gaB + kb2 + (size_t)(32 * j) * D_MODEL, sB + (t + 256 * j) * 8);
      FENCE();
#pragma unroll
      for (int j = 0; j < 4; ++j) {
        uint4 v4 = {cv[j][0], cv[j][1], cv[j][2], cv[j][3]};
        *(uint4*)&sA[(t + 256 * j) * 8] = v4;
      }
    }
  }
  __syncthreads();  // full drain before smem reuse as sC

  u16* sC = smem;
  if (z == 2) {
    // sC[col][s-row], stride 136 (row index reaches 127)
#pragma unroll
    for (int j = 0; j < 2; ++j) {
      const int col = wn + j * 16 + c;
      const float bv = bias[n0 + col];
#pragma unroll
      for (int i = 0; i < 4; ++i)
#pragma unroll
        for (int r = 0; r < 4; ++r)
          sC[col * 136 + wm + i * 16 + qd * 4 + r] = f2bf(acc[i][j][r] + bv);
    }
    __syncthreads();
    u16* VT = Cout + ((size_t)2 << 22);
    const int bb = m0 >> 11, s0v = m0 & 2047;
    const int sidx = (t & 15) * 8;
#pragma unroll
    for (int outer = 0; outer < 4; ++outer) {
      const int vrow = outer * 16 + (t >> 4);  // 0..63
      const int colg = n0 + vrow;
      const int hh = colg >> 6, dd = colg & 63;
      uint4 val = *(const uint4*)&sC[vrow * 136 + sidx];
      *(uint4*)&VT[((size_t)((bb * NHEAD + hh) * DK + dd)) * SEQ + s0v + sidx] =
          val;
    }
  } else {
    // sC[row][col], stride 72 (col < 64)
#pragma unroll
    for (int j = 0; j < 2; ++j) {
      const int col = wn + j * 16 + c;
      const float bv = bias[n0 + col];
#pragma unroll
      for (int i = 0; i < 4; ++i)
#pragma unroll
        for (int r = 0; r < 4; ++r)
          sC[(wm + i * 16 + qd * 4 + r) * 72 + col] =
              f2bf((acc[i][j][r] + bv) * scl);
    }
    __syncthreads();
    u16* outp = Cout + ((size_t)z << 22);
    const int cidx = (t & 7) * 8;
#pragma unroll
    for (int outer = 0; outer < 4; ++outer) {
      const int lrow = outer * 32 + (t >> 3);  // 0..127
      uint4 val = *(const uint4*)&sC[lrow * 72 + cidx];
      *(uint4*)&outp[(size_t)(m0 + lrow) * D_MODEL + n0 + cidx] = val;
    }
  }
}

// ---------------------------------------------------------------------------
// Kernel 3: compact V^T along s: VTc[row][j] = VT[row][idx[b][j]], j<cnt[b].
// ---------------------------------------------------------------------------
__global__ __launch_bounds__(256) void vtc_gather(const u16* __restrict__ VT,
                                                  const int* __restrict__ idx,
                                                  const int* __restrict__ cnt,
                                                  u16* __restrict__ VTc) {
  const int row = blockIdx.x;  // (b*16+h)*64+d in [0,2048)
  const int b = row >> 10;
  const int cn = cnt[b];
  const u16* src = VT + (size_t)row * SEQ;
  u16* dst = VTc + (size_t)row * SEQ;
  const int* ib = idx + b * SEQ;
  for (int j = threadIdx.x; j < cn; j += 256) dst[j] = src[ib[j]];
}

// ---------------------------------------------------------------------------
// Kernel 4: flash attention over COMPACTED live keys.  S^T orientation,
// fixed-max softmax (m=16, exp2 domain).  Split-K x2, pipelined prefetch.
// ---------------------------------------------------------------------------
__global__ __launch_bounds__(256) void mha_attn(
    const u16* __restrict__ QKVb, const u16* __restrict__ VTc,
    const int* __restrict__ idx, const int* __restrict__ cnt,
    u16* __restrict__ Opart, float* __restrict__ ml) {
  __shared__ __align__(16) u16 sK[64 * 72];
  __shared__ __align__(16) u16 sVt[64 * 72];   // [d][key]
  __shared__ __align__(16) u16 sP[128 * 72];   // [q][key] = P^T rows

  const int t = threadIdx.x, lane = t & 63, wq = t >> 6;
  const int c = lane & 15, qd = lane >> 4;
  const int qb = blockIdx.x, h = blockIdx.y;
  const int b = blockIdx.z & 1, ck = blockIdx.z >> 1;

  const int cn = cnt[b];
  const int nb = (cn + 63) >> 6;
  const int half = (nb + 1) >> 1;
  const int kstart = ck ? half : 0;
  const int kend = ck ? nb : half;

  const u16* Qg = QKVb;
  const u16* Kg = QKVb + ((size_t)4 << 20);
  const u16* VTch = VTc + ((size_t)((b * NHEAD + h) * DK)) * SEQ;
  const int rowbase = b * SEQ;
  const int colbase = h * DK;

  // ---- Q B-fragments direct from global (lane n=q=c, k=qd*8+j) ----
  bf16x8 aq[2][2];
#pragma unroll
  for (int qt = 0; qt < 2; ++qt) {
    const u16* g = Qg +
                   (size_t)(rowbase + qb * 128 + wq * 32 + qt * 16 + c) * D_MODEL +
                   colbase + qd * 8;
    aq[qt][0] = *(const bf16x8*)g;
    aq[qt][1] = *(const bf16x8*)(g + 32);
  }

  float l[2] = {0.f, 0.f};
  f32x4 o[2][4] = {};
  const float MADD = -1.4426950e9f;  // NEG_INF * log2(e)
  const float MFIX = 16.0f;          // fixed softmax max (exp2 domain)

  const int r0s = t >> 2, offs = (t & 3) * 16;
  const u16* gvb = VTch + (size_t)r0s * SEQ + offs;
  const int* idxb = idx + b * SEQ + r0s;

  uint4 k0, k1, v0, v1;
  int sNext2 = 0;
  if (kstart < kend) {
    const int s0i = idxb[kstart * 64];
    const u16* gk = Kg + (size_t)(rowbase + s0i) * D_MODEL + colbase + offs;
    const u16* gv = gvb + kstart * 64;
    k0 = *(const uint4*)gk;
    k1 = *(const uint4*)(gk + 8);
    v0 = *(const uint4*)gv;
    v1 = *(const uint4*)(gv + 8);
    if (kstart + 1 < kend) sNext2 = idxb[(kstart + 1) * 64];
  }

  for (int kbi = kstart; kbi < kend; ++kbi) {
    __syncthreads();  // previous iteration's sK/sVt reads complete
    *(uint4*)&sK[r0s * 72 + offs] = k0;
    *(uint4*)&sK[r0s * 72 + offs + 8] = k1;
    *(uint4*)&sVt[r0s * 72 + offs] = v0;
    *(uint4*)&sVt[r0s * 72 + offs + 8] = v1;
    __syncthreads();
    // prefetch next: K via idx loaded a full iteration earlier
    if (kbi + 1 < kend) {
      const u16* gk = Kg + (size_t)(rowbase + sNext2) * D_MODEL + colbase + offs;
      const u16* gv = gvb + (kbi + 1) * 64;
      k0 = *(const uint4*)gk;
      k1 = *(const uint4*)(gk + 8);
      v0 = *(const uint4*)gv;
      v1 = *(const uint4*)(gv + 8);
    }
    if (kbi + 2 < kend) sNext2 = idxb[(kbi + 2) * 64];

    // ---- S^T = K Q^T (+ pad mask on last partial block) ----
    const bool full = ((kbi + 1) << 6) <= cn;
    f32x4 st[2][4];
#pragma unroll
    for (int tt = 0; tt < 4; ++tt) {
      bf16x8 ak0 = *(const bf16x8*)&sK[(tt * 16 + c) * 72 + qd * 8];
      bf16x8 ak1 = *(const bf16x8*)&sK[(tt * 16 + c) * 72 + qd * 8 + 32];
      f32x4 cin;
      if (full) {
        cin = f32x4{0.f, 0.f, 0.f, 0.f};
      } else {
        const int jb = (kbi << 6) + tt * 16 + qd * 4;
        cin = f32x4{jb + 0 < cn ? 0.f : MADD, jb + 1 < cn ? 0.f : MADD,
                    jb + 2 < cn ? 0.f : MADD, jb + 3 < cn ? 0.f : MADD};
      }
#pragma unroll
      for (int qt = 0; qt < 2; ++qt) {
        f32x4 a =
            __builtin_amdgcn_mfma_f32_16x16x32_bf16(ak0, aq[qt][0], cin, 0, 0, 0);
        a = __builtin_amdgcn_mfma_f32_16x16x32_bf16(ak1, aq[qt][1], a, 0, 0, 0);
        st[qt][tt] = a;
      }
    }

    // ---- softmax numerator: p = exp2(s - MFIX) ----
#pragma unroll
    for (int qt = 0; qt < 2; ++qt) {
      float sum = 0.f;
      const int prow = (wq * 32 + qt * 16 + c) * 72;
#pragma unroll
      for (int tt = 0; tt < 4; ++tt) {
        u32 pk[2];
#pragma unroll
        for (int pr = 0; pr < 2; ++pr) {
          u32 p0 = __builtin_bit_cast(u32, fast_exp2(st[qt][tt][2 * pr] - MFIX));
          u32 p1 =
              __builtin_bit_cast(u32, fast_exp2(st[qt][tt][2 * pr + 1] - MFIX));
          u32 hi1 = p1 & 0xffff0000u;
          pk[pr] = (p0 >> 16) | hi1;
          sum += __builtin_bit_cast(float, p0 & 0xffff0000u);
          sum += __builtin_bit_cast(float, hi1);
        }
        uint2 pv2 = {pk[0], pk[1]};
        *(uint2*)&sP[prow + tt * 16 + qd * 4] = pv2;  // ds_write_b64
      }
      l[qt] += sum;
    }

    // ---- O^T += V^T P^T ----
    bf16x8 bp[2][2];
#pragma unroll
    for (int qt = 0; qt < 2; ++qt) {
      const int prow = (wq * 32 + qt * 16 + c) * 72;
      bp[qt][0] = *(const bf16x8*)&sP[prow + qd * 8];
      bp[qt][1] = *(const bf16x8*)&sP[prow + qd * 8 + 32];
    }
#pragma unroll
    for (int dt = 0; dt < 4; ++dt) {
      bf16x8 av0 = *(const bf16x8*)&sVt[(dt * 16 + c) * 72 + qd * 8];
      bf16x8 av1 = *(const bf16x8*)&sVt[(dt * 16 + c) * 72 + qd * 8 + 32];
#pragma unroll
      for (int qt = 0; qt < 2; ++qt) {
        o[qt][dt] =
            __builtin_amdgcn_mfma_f32_16x16x32_bf16(av0, bp[qt][0], o[qt][dt], 0, 0, 0);
        o[qt][dt] =
            __builtin_amdgcn_mfma_f32_16x16x32_bf16(av1, bp[qt][1], o[qt][dt], 0, 0, 0);
      }
    }
  }

  // ---- epilogue ----
  const size_t obase =
      (size_t)ck * 4194304 + ((size_t)((b * NHEAD + h) * SEQ) + qb * 128) * 64;
  const int mlbase = ((ck * 2 + b) * NHEAD + h) * SEQ + qb * 128;
#pragma unroll
  for (int qt = 0; qt < 2; ++qt) {
    float ls = l[qt];
    ls += __shfl_xor(ls, 16);
    ls += __shfl_xor(ls, 32);
    const float inv = (ls != 0.f) ? 1.0f / ls : 0.f;
    const int q = wq * 32 + qt * 16 + c;
#pragma unroll
    for (int dt = 0; dt < 4; ++dt) {
      u32 lo = (u32)f2bf(o[qt][dt][0] * inv) |
               ((u32)f2bf(o[qt][dt][1] * inv) << 16);
      u32 hi = (u32)f2bf(o[qt][dt][2] * inv) |
               ((u32)f2bf(o[qt][dt][3] * inv) << 16);
      uint2 ov = {lo, hi};
      *(uint2*)&Opart[obase + (size_t)q * 64 + dt * 16 + qd * 4] = ov;
    }
    if (qd == 0) ml[mlbase + q] = ls;
  }
}

// ---------------------------------------------------------------------------
// Kernel 5: combine the two key-chunk partials -> ctx bf16
// ---------------------------------------------------------------------------
__global__ __launch_bounds__(256) void mha_combine(
    const u16* __restrict__ Opart, const float* __restrict__ ml,
    u16* __restrict__ ctx) {
  const int tid = blockIdx.x * 256 + threadIdx.x;  // 524288 = 65536 rows x 8
  const int row = tid >> 3, d0 = (tid & 7) * 8;
  const int b = row >> 15, h = (row >> 11) & 15, q = row & 2047;
  float l1 = ml[row];
  float l2 = ml[65536 + row];
  float inv = 1.0f / (l1 + l2);
  float w1 = l1 * inv, w2 = l2 * inv;
  const size_t o1 = (size_t)row * 64 + d0;
  uint4 pa = *(const uint4*)(Opart + o1);
  uint4 pb = *(const uint4*)(Opart + 4194304 + o1);
  u32 wa[4] = {pa.x, pa.y, pa.z, pa.w};
  u32 wb[4] = {pb.x, pb.y, pb.z, pb.w};
  u32 out[4];
#pragma unroll
  for (int j = 0; j < 4; ++j) {
    float alo = __builtin_bit_cast(float, wa[j] << 16);
    float ahi = __builtin_bit_cast(float, wa[j] & 0xffff0000u);
    float blo = __builtin_bit_cast(float, wb[j] << 16);
    float bhi = __builtin_bit_cast(float, wb[j] & 0xffff0000u);
    float rlo = w1 * alo + w2 * blo;
    float rhi = w1 * ahi + w2 * bhi;
    out[j] = (u32)f2bf(rlo) | ((u32)f2bf(rhi) << 16);
  }
  uint4 ov = {out[0], out[1], out[2], out[3]};
  *(uint4*)&ctx[((size_t)(b * SEQ + q)) * D_MODEL + h * DK + d0] = ov;
}

// ---------------------------------------------------------------------------
// Kernel 6: output projection, fp32 out.  128x64 tile, BK=64, grid (32,16).
// TRIPLE-BUFFERED 2-DEEP COUNTED-VMCNT PIPELINE (pure gload16, zero staging
// registers).  Proven round 6.
// ---------------------------------------------------------------------------
__global__ __launch_bounds__(256) void gemm_out(
    const u16* __restrict__ A, const u16* __restrict__ Bw,
    const float* __restrict__ bias, float* __restrict__ Cout) {
  __shared__ __align__(16) u16 sAb[3][128 * 64];  // 48KB
  __shared__ __align__(16) u16 sBc[3][64 * 64];   // 24KB

  const int t = threadIdx.x;
  const int m0 = blockIdx.x * 128, n0 = blockIdx.y * 64;
  const int lane = t & 63, wv = t >> 6;
  const int wm = (wv >> 1) * 64, wn = (wv & 1) * 32;
  const int c = lane & 15, qd = lane >> 4;

  const int arow = t >> 3;
  const int aoff = (((t & 7) - arow) & 7) * 8;
  const u16* gaA = A + (size_t)(m0 + arow) * D_MODEL + aoff;
  const u16* gaB = Bw + (size_t)(n0 + arow) * D_MODEL + aoff;

  // ---- prologue: L(0):6, L(1):6 ----
#pragma unroll
  for (int j = 0; j < 4; ++j)
    gload16(gaA + (size_t)(32 * j) * D_MODEL, &sAb[0][(t + 256 * j) * 8]);
#pragma unroll
  for (int j = 0; j < 2; ++j)
    gload16(gaB + (size_t)(32 * j) * D_MODEL, &sBc[0][(t + 256 * j) * 8]);
  FENCE();
#pragma unroll
  for (int j = 0; j < 4; ++j)
    gload16(gaA + 64 + (size_t)(32 * j) * D_MODEL, &sAb[1][(t + 256 * j) * 8]);
#pragma unroll
  for (int j = 0; j < 2; ++j)
    gload16(gaB + 64 + (size_t)(32 * j) * D_MODEL, &sBc[1][(t + 256 * j) * 8]);
  FENCE();

  f32x4 acc[4][2] = {};

  for (int kbi = 0; kbi < 16; ++kbi) {
    const int cur = kbi % 3;
    // retire L(kbi):6; keep L(kbi+1):6 in flight (tail: drain)
    if (kbi == 15) { WVL(0); } else { WVL(6); }
    SBAR();
    if (kbi + 2 < 16) {
      const int nxt = (kbi + 2) % 3;
      const int kb2 = (kbi + 2) * 64;
#pragma unroll
      for (int j = 0; j < 4; ++j)
        gload16(gaA + kb2 + (size_t)(32 * j) * D_MODEL,
                &sAb[nxt][(t + 256 * j) * 8]);
#pragma unroll
      for (int j = 0; j < 2; ++j)
        gload16(gaB + kb2 + (size_t)(32 * j) * D_MODEL,
                &sBc[nxt][(t + 256 * j) * 8]);
      FENCE();
    }
    const u16* sA = sAb[cur];
    const u16* sB = sBc[cur];
#pragma unroll
    for (int s = 0; s < 2; ++s) {
      const int ao = ((s * 4 + qd + wm + c) & 7) * 8;
      const int bo = ((s * 4 + qd + wn + c) & 7) * 8;
      bf16x8 af[4], bfr[2];
#pragma unroll
      for (int i = 0; i < 4; ++i)
        af[i] = *(const bf16x8*)&sA[(wm + i * 16 + c) * 64 + ao];
#pragma unroll
      for (int j = 0; j < 2; ++j)
        bfr[j] = *(const bf16x8*)&sB[(wn + j * 16 + c) * 64 + bo];
#pragma unroll
      for (int i = 0; i < 4; ++i)
#pragma unroll
        for (int j = 0; j < 2; ++j)
          acc[i][j] = __builtin_amdgcn_mfma_f32_16x16x32_bf16(af[i], bfr[j],
                                                              acc[i][j], 0, 0, 0);
    }
  }

#pragma unroll
  for (int j = 0; j < 2; ++j) {
    const int col = n0 + wn + j * 16 + c;
    const float bv = bias[col];
#pragma unroll
    for (int i = 0; i < 4; ++i)
#pragma unroll
      for (int r = 0; r < 4; ++r) {
        const int row = m0 + wm + i * 16 + qd * 4 + r;
        Cout[(size_t)row * D_MODEL + col] = acc[i][j][r] + bv;
      }
  }
}

// ---------------------------------------------------------------------------
extern "C" void kernel_launch(void* const* d_in, const int* in_sizes, int n_in,
                              void* d_out, int out_size, void* d_ws,
                              size_t ws_size, hipStream_t stream) {
  const float* query = (const float*)d_in[0];
  const float* key   = (const float*)d_in[1];
  const float* value = (const float*)d_in[2];
  const int*   mask  = (const int*)d_in[3];
  const float* Wq = (const float*)d_in[4];
  const float* bq = (const float*)d_in[5];
  const float* Wk = (const float*)d_in[6];
  const float* bk = (const float*)d_in[7];
  const float* Wv = (const float*)d_in[8];
  const float* bv = (const float*)d_in[9];
  const float* Wo = (const float*)d_in[10];
  const float* bo = (const float*)d_in[11];

  // ws (u16 units, 32M = 64 MB):
  //   [0..4M)   VTc          [4M..12M)  Opart
  //   [12M..16M) Wb: Wq/Wk/Wv bf16 (dead after gemm_qkv; ml aliases Wq), Wo live
  //   [16M..28M) QKV: Q | K | VT(orig)   [28M..32M) CTX (idx/cnt alias early)
  u16* ws  = (u16*)d_ws;
  u16* Wb  = ws + ((size_t)12 << 20);
  u16* QKV = ws + ((size_t)16 << 20);
  u16* CTX = ws + ((size_t)28 << 20);
  u16* VTc = ws;
  u16* Opart = ws + ((size_t)4 << 20);
  float* ml = (float*)(ws + ((size_t)12 << 20));
  int* idxp = (int*)(ws + ((size_t)28 << 20));
  int* cntp = idxp + 2 * SEQ;

  mask_scan<<<dim3(2), dim3(256), 0, stream>>>(mask, idxp, cntp);
  w_convert<<<dim3(1024), dim3(256), 0, stream>>>(Wq, Wk, Wv, Wo, Wb);
  gemm_qkv<<<dim3(32, 16, 3), dim3(256), 0, stream>>>(query, key, value, Wb, bq,
                                                      bk, bv, QKV);
  vtc_gather<<<dim3(2048), dim3(256), 0, stream>>>(QKV + ((size_t)8 << 20), idxp,
                                                   cntp, VTc);
  mha_attn<<<dim3(16, 16, 4), dim3(256), 0, stream>>>(QKV, VTc, idxp, cntp,
                                                      Opart, ml);
  mha_combine<<<dim3(2048), dim3(256), 0, stream>>>(Opart, ml, CTX);
  gemm_out<<<dim3(32, 16), dim3(256), 0, stream>>>(CTX, Wb + ((size_t)3 << 20),
                                                   bo, (float*)d_out);
}

// Round 8
// 213.999 us; speedup vs baseline: 1.9136x; 1.9136x over previous
//
#include <hip/hip_runtime.h>
#include <cstdint>
#include <cstddef>

typedef unsigned short u16;
typedef unsigned int   u32;
typedef __bf16 bf16x8 __attribute__((ext_vector_type(8)));
typedef float  f32x4  __attribute__((ext_vector_type(4)));

#define D_MODEL 1024
#define SEQ     2048
#define NTOK    4096   // B*S
#define NHEAD   16
#define DK      64

// raw sync primitives for counted-vmcnt pipelines (no vmcnt(0) drains in-loop)
#define FENCE() asm volatile("" ::: "memory")
#define SBAR()  asm volatile("s_barrier" ::: "memory")
#define WVL(N)  asm volatile("s_waitcnt vmcnt(" #N ") lgkmcnt(0)" ::: "memory")

// hardware exp2 (v_exp_f32)
__device__ __forceinline__ float fast_exp2(float x) {
  return __builtin_amdgcn_exp2f(x);
}

// fp32 -> bf16 round-to-nearest-even (bit version, for memory-bound kernels)
__device__ __forceinline__ u16 f2bf(float f) {
  u32 u = __builtin_bit_cast(u32, f);
  u += 0x7fffu + ((u >> 16) & 1u);
  return (u16)(u >> 16);
}

// packed fp32x2 -> bf16x2 via compiler casts (lowers to v_cvt_pk_bf16_f32)
__device__ __forceinline__ u32 pkbf(float a, float b) {
  u16 x = __builtin_bit_cast(u16, (__bf16)a);
  u16 y = __builtin_bit_cast(u16, (__bf16)b);
  return (u32)x | ((u32)y << 16);
}

// async global->LDS, 16B per lane (dest must be wave-uniform base + lane*16)
__device__ __forceinline__ void gload16(const u16* g, u16* l) {
  __builtin_amdgcn_global_load_lds(
      (__attribute__((address_space(1))) void*)(uintptr_t)g,
      (__attribute__((address_space(3))) void*)l,
      16, 0, 0);
}

// ---------------------------------------------------------------------------
// Kernel 0: per-batch mask compaction scan.  idx[b][j] = s of j-th live key,
// cnt[b] = #live; idx pads (j>=cnt) = 0.
// ---------------------------------------------------------------------------
__global__ __launch_bounds__(256) void mask_scan(const int* __restrict__ mask,
                                                 int* __restrict__ idx,
                                                 int* __restrict__ cnt) {
  const int b = blockIdx.x, t = threadIdx.x;
  const int lane = t & 63, w = t >> 6;
  __shared__ int sW[4];
  __shared__ int sTot;
  int m8[8];
  const int base = b * SEQ + t * 8;
  int tot = 0;
#pragma unroll
  for (int i = 0; i < 8; ++i) {
    m8[i] = (mask[base + i] != 0);
    tot += m8[i];
  }
  int v = tot;  // wave inclusive scan
#pragma unroll
  for (int d = 1; d < 64; d <<= 1) {
    int u = __shfl_up(v, d);
    if (lane >= d) v += u;
  }
  if (lane == 63) sW[w] = v;
  __syncthreads();
  if (t == 0) {
    int run = 0;
#pragma unroll
    for (int i = 0; i < 4; ++i) { int tmp = sW[i]; sW[i] = run; run += tmp; }
    sTot = run;
  }
  __syncthreads();
  int pos = v - tot + sW[w];  // exclusive prefix for this thread
#pragma unroll
  for (int i = 0; i < 8; ++i)
    if (m8[i]) idx[b * SEQ + pos++] = t * 8 + i;
  const int cn = sTot;
  if (t == 0) cnt[b] = cn;
  for (int j = cn + t; j < SEQ; j += 256) idx[b * SEQ + j] = 0;
}

// ---------------------------------------------------------------------------
// Kernel 1: fp32 -> bf16 conversion for WEIGHTS only (4 x 1M)
// ---------------------------------------------------------------------------
__global__ __launch_bounds__(256) void w_convert(
    const float* __restrict__ wq, const float* __restrict__ wk,
    const float* __restrict__ wv, const float* __restrict__ wo,
    u16* __restrict__ wb) {
  const int total = 1 << 20;  // float4 chunks: 4 * 2^18
  for (int cid = blockIdx.x * blockDim.x + threadIdx.x; cid < total;
       cid += gridDim.x * blockDim.x) {
    int which = cid >> 18;
    int off = cid & ((1 << 18) - 1);
    const float* src = which == 0 ? wq : (which == 1 ? wk : (which == 2 ? wv : wo));
    u16* dst = wb + ((size_t)which << 20);
    float4 f = ((const float4*)src)[off];
    ushort4 u;
    u.x = f2bf(f.x); u.y = f2bf(f.y); u.z = f2bf(f.z); u.w = f2bf(f.w);
    ((ushort4*)dst)[off] = u;
  }
}

// ---------------------------------------------------------------------------
// Kernel 2: QKV projections reading fp32 inputs DIRECTLY (conversion fused).
// C[M,N] = A[M,K]*B[N,K]^T + bias, bf16 out.  128x128 tile, BK=64.
// COUNTED-VMCNT PIPELINE (raw s_barrier, no vmcnt(0) drains in-loop):
//   B: gload16 -> sB dbuf, issued post-barrier, waited with vmcnt(8) a full
//      step later.  A: fp32 reg-staged "1.5-deep"; cvt_pk -> sA.
// FIFO: each step issues B(k+1):4 then A(k+2):8; loop-top WVL(8) retires
// B(k); post-MFMA WVL(4) retires A(k+1).  Rotated k-slots, conflict-free.
// VERIFIED 49.3us (round 4/6).  Round-5 (A-direct, coalescing loss) and
// round-7 (128x64 @ launch_bounds(256,6): VGPR capped 40 -> 292MB spill)
// both regressed -- do NOT shrink tile or raise min-occupancy here.
// z==0: Q scaled by 0.125*log2(e).  z==2: V transposed [b][h][d][s].
// ---------------------------------------------------------------------------
__global__ __launch_bounds__(256, 3) void gemm_qkv(
    const float* __restrict__ Aq, const float* __restrict__ Ak,
    const float* __restrict__ Av, const u16* __restrict__ Bw,
    const float* __restrict__ b0, const float* __restrict__ b1,
    const float* __restrict__ b2, u16* __restrict__ Cout) {
  __shared__ __align__(16) u16 smem[3 * 128 * 64];  // sA | sB0 | sB1; epi: sC
  u16* sA = smem;

  const int t = threadIdx.x;
  const int z = blockIdx.z;
  const float* Ap = (z == 0) ? Aq : ((z == 1) ? Ak : Av);
  const u16* Bp = Bw + ((size_t)z << 20);
  const float* bias = (z == 0) ? b0 : ((z == 1) ? b1 : b2);
  const float scl = (z == 0) ? 0.18033688011f : 1.0f;

  const int m0 = blockIdx.x * 128, n0 = blockIdx.y * 128;
  const int lane = t & 63, wv = t >> 6;
  const int wm = (wv >> 1) * 64, wn = (wv & 1) * 64;
  const int c = lane & 15, qd = lane >> 4;

  // staging: chunk cc = t + 256j -> row = cc>>3, phys slot t&7, source
  // k-slot rotated by row (32j = 0 mod 8 -> j-invariant)
  const int arow = t >> 3;
  const int aoff = (((t & 7) - arow) & 7) * 8;
  const float* gaA = Ap + (size_t)(m0 + arow) * D_MODEL + aoff;
  const u16* gaB = Bp + (size_t)(n0 + arow) * D_MODEL + aoff;

  float4 pa[4][2];
  u32 cv[4][4];

  // ---- prologue: issue A(0):8, B(0):4; convert A(0); issue A(1):8 ----
#pragma unroll
  for (int j = 0; j < 4; ++j) {
    pa[j][0] = *(const float4*)(gaA + (size_t)(32 * j) * D_MODEL);
    pa[j][1] = *(const float4*)(gaA + (size_t)(32 * j) * D_MODEL + 4);
  }
  FENCE();
#pragma unroll
  for (int j = 0; j < 4; ++j)
    gload16(gaB + (size_t)(32 * j) * D_MODEL, smem + 8192 + (t + 256 * j) * 8);
  WVL(4);  // A(0) arrived (B(0):4 outstanding)
#pragma unroll
  for (int j = 0; j < 4; ++j) {
    cv[j][0] = pkbf(pa[j][0].x, pa[j][0].y);
    cv[j][1] = pkbf(pa[j][0].z, pa[j][0].w);
    cv[j][2] = pkbf(pa[j][1].x, pa[j][1].y);
    cv[j][3] = pkbf(pa[j][1].z, pa[j][1].w);
  }
  FENCE();
#pragma unroll
  for (int j = 0; j < 4; ++j) {  // issue A(1):8
    pa[j][0] = *(const float4*)(gaA + 64 + (size_t)(32 * j) * D_MODEL);
    pa[j][1] = *(const float4*)(gaA + 64 + (size_t)(32 * j) * D_MODEL + 4);
  }
  FENCE();
#pragma unroll
  for (int j = 0; j < 4; ++j) {
    uint4 v4 = {cv[j][0], cv[j][1], cv[j][2], cv[j][3]};
    *(uint4*)&sA[(t + 256 * j) * 8] = v4;
  }

  f32x4 acc[4][4] = {};

#pragma unroll
  for (int kbi = 0; kbi < 16; ++kbi) {
    const int cur = kbi & 1;
    // loop-top: B(kbi) in LDS (retire it; keep A(kbi+1):8 in flight);
    // lgkmcnt(0) drains our sA ds_writes before the barrier.
    if (kbi == 15) { WVL(0); } else { WVL(8); }
    SBAR();
    // issue B(kbi+1) -> other sB buffer; flies across the whole step
    if (kbi + 1 < 16) {
      u16* sBn = smem + 8192 + (1 - cur) * 8192;
      const int kb2 = (kbi + 1) * 64;
#pragma unroll
      for (int j = 0; j < 4; ++j)
        gload16(gaB + kb2 + (size_t)(32 * j) * D_MODEL, sBn + (t + 256 * j) * 8);
    }
    FENCE();
    const u16* sB = smem + 8192 + cur * 8192;
#pragma unroll
    for (int s = 0; s < 2; ++s) {
      const int ao = ((s * 4 + qd + wm + c) & 7) * 8;  // rotated k-slot
      const int bo = ((s * 4 + qd + wn + c) & 7) * 8;
      bf16x8 af[4], bfr[4];
#pragma unroll
      for (int i = 0; i < 4; ++i)
        af[i] = *(const bf16x8*)&sA[(wm + i * 16 + c) * 64 + ao];
#pragma unroll
      for (int j = 0; j < 4; ++j)
        bfr[j] = *(const bf16x8*)&sB[(wn + j * 16 + c) * 64 + bo];
#pragma unroll
      for (int i = 0; i < 4; ++i)
#pragma unroll
        for (int j = 0; j < 4; ++j)
          acc[i][j] = __builtin_amdgcn_mfma_f32_16x16x32_bf16(af[i], bfr[j],
                                                              acc[i][j], 0, 0, 0);
    }
    if (kbi + 1 < 16) {
      WVL(4);  // A(kbi+1) regs arrived (B(kbi+1):4 outstanding)
#pragma unroll
      for (int j = 0; j < 4; ++j) {
        cv[j][0] = pkbf(pa[j][0].x, pa[j][0].y);
        cv[j][1] = pkbf(pa[j][0].z, pa[j][0].w);
        cv[j][2] = pkbf(pa[j][1].x, pa[j][1].y);
        cv[j][3] = pkbf(pa[j][1].z, pa[j][1].w);
      }
      if (kbi + 2 < 16) {  // issue A(kbi+2):8 into freed fp32 regs
        const int kb3 = (kbi + 2) * 64;
#pragma unroll
        for (int j = 0; j < 4; ++j) {
          pa[j][0] = *(const float4*)(gaA + kb3 + (size_t)(32 * j) * D_MODEL);
          pa[j][1] = *(const float4*)(gaA + kb3 + (size_t)(32 * j) * D_MODEL + 4);
        }
      }
      FENCE();
      SBAR();  // all waves done reading sA(kbi)
#pragma unroll
      for (int j = 0; j < 4; ++j) {
        uint4 v4 = {cv[j][0], cv[j][1], cv[j][2], cv[j][3]};
        *(uint4*)&sA[(t + 256 * j) * 8] = v4;
      }
    }
  }
  __syncthreads();  // full drain before smem reuse as sC

  u16* sC = smem;  // stride 136
  if (z == 2) {
#pragma unroll
    for (int j = 0; j < 4; ++j) {
      const int col = wn + j * 16 + c;
      const float bv = bias[n0 + col];
#pragma unroll
      for (int i = 0; i < 4; ++i)
#pragma unroll
        for (int r = 0; r < 4; ++r)
          sC[col * 136 + wm + i * 16 + qd * 4 + r] = f2bf(acc[i][j][r] + bv);
    }
    __syncthreads();
    u16* VT = Cout + ((size_t)2 << 22);
    const int bb = m0 >> 11, s0 = m0 & 2047;
    const int sidx = (t & 15) * 8;
#pragma unroll
    for (int outer = 0; outer < 8; ++outer) {
      const int vrow = outer * 16 + (t >> 4);
      const int col = n0 + vrow;
      const int hh = col >> 6, dd = col & 63;
      uint4 val = *(const uint4*)&sC[vrow * 136 + sidx];
      *(uint4*)&VT[((size_t)((bb * NHEAD + hh) * DK + dd)) * SEQ + s0 + sidx] =
          val;
    }
  } else {
#pragma unroll
    for (int j = 0; j < 4; ++j) {
      const int col = wn + j * 16 + c;
      const float bv = bias[n0 + col];
#pragma unroll
      for (int i = 0; i < 4; ++i)
#pragma unroll
        for (int r = 0; r < 4; ++r)
          sC[(wm + i * 16 + qd * 4 + r) * 136 + col] =
              f2bf((acc[i][j][r] + bv) * scl);
    }
    __syncthreads();
    u16* outp = Cout + ((size_t)z << 22);
    const int cidx = (t & 15) * 8;
#pragma unroll
    for (int outer = 0; outer < 8; ++outer) {
      const int lrow = outer * 16 + (t >> 4);
      uint4 val = *(const uint4*)&sC[lrow * 136 + cidx];
      *(uint4*)&outp[(size_t)(m0 + lrow) * D_MODEL + n0 + cidx] = val;
    }
  }
}

// ---------------------------------------------------------------------------
// Kernel 3: compact V^T along s: VTc[row][j] = VT[row][idx[b][j]], j<cnt[b].
// ---------------------------------------------------------------------------
__global__ __launch_bounds__(256) void vtc_gather(const u16* __restrict__ VT,
                                                  const int* __restrict__ idx,
                                                  const int* __restrict__ cnt,
                                                  u16* __restrict__ VTc) {
  const int row = blockIdx.x;  // (b*16+h)*64+d in [0,2048)
  const int b = row >> 10;
  const int cn = cnt[b];
  const u16* src = VT + (size_t)row * SEQ;
  u16* dst = VTc + (size_t)row * SEQ;
  const int* ib = idx + b * SEQ;
  for (int j = threadIdx.x; j < cn; j += 256) dst[j] = src[ib[j]];
}

// ---------------------------------------------------------------------------
// Kernel 4: flash attention over COMPACTED live keys.  S^T orientation,
// fixed-max softmax (m=16, exp2 domain).  Split-K x2, pipelined prefetch.
// T5 setprio around MFMA clusters (m191: attn independent-block regime
// measured +4-7%).
// ---------------------------------------------------------------------------
__global__ __launch_bounds__(256) void mha_attn(
    const u16* __restrict__ QKVb, const u16* __restrict__ VTc,
    const int* __restrict__ idx, const int* __restrict__ cnt,
    u16* __restrict__ Opart, float* __restrict__ ml) {
  __shared__ __align__(16) u16 sK[64 * 72];
  __shared__ __align__(16) u16 sVt[64 * 72];   // [d][key]
  __shared__ __align__(16) u16 sP[128 * 72];   // [q][key] = P^T rows

  const int t = threadIdx.x, lane = t & 63, wq = t >> 6;
  const int c = lane & 15, qd = lane >> 4;
  const int qb = blockIdx.x, h = blockIdx.y;
  const int b = blockIdx.z & 1, ck = blockIdx.z >> 1;

  const int cn = cnt[b];
  const int nb = (cn + 63) >> 6;
  const int half = (nb + 1) >> 1;
  const int kstart = ck ? half : 0;
  const int kend = ck ? nb : half;

  const u16* Qg = QKVb;
  const u16* Kg = QKVb + ((size_t)4 << 20);
  const u16* VTch = VTc + ((size_t)((b * NHEAD + h) * DK)) * SEQ;
  const int rowbase = b * SEQ;
  const int colbase = h * DK;

  // ---- Q B-fragments direct from global (lane n=q=c, k=qd*8+j) ----
  bf16x8 aq[2][2];
#pragma unroll
  for (int qt = 0; qt < 2; ++qt) {
    const u16* g = Qg +
                   (size_t)(rowbase + qb * 128 + wq * 32 + qt * 16 + c) * D_MODEL +
                   colbase + qd * 8;
    aq[qt][0] = *(const bf16x8*)g;
    aq[qt][1] = *(const bf16x8*)(g + 32);
  }

  float l[2] = {0.f, 0.f};
  f32x4 o[2][4] = {};
  const float MADD = -1.4426950e9f;  // NEG_INF * log2(e)
  const float MFIX = 16.0f;          // fixed softmax max (exp2 domain)

  const int r0s = t >> 2, offs = (t & 3) * 16;
  const u16* gvb = VTch + (size_t)r0s * SEQ + offs;
  const int* idxb = idx + b * SEQ + r0s;

  uint4 k0, k1, v0, v1;
  int sNext2 = 0;
  if (kstart < kend) {
    const int s0i = idxb[kstart * 64];
    const u16* gk = Kg + (size_t)(rowbase + s0i) * D_MODEL + colbase + offs;
    const u16* gv = gvb + kstart * 64;
    k0 = *(const uint4*)gk;
    k1 = *(const uint4*)(gk + 8);
    v0 = *(const uint4*)gv;
    v1 = *(const uint4*)(gv + 8);
    if (kstart + 1 < kend) sNext2 = idxb[(kstart + 1) * 64];
  }

  for (int kbi = kstart; kbi < kend; ++kbi) {
    __syncthreads();  // previous iteration's sK/sVt reads complete
    *(uint4*)&sK[r0s * 72 + offs] = k0;
    *(uint4*)&sK[r0s * 72 + offs + 8] = k1;
    *(uint4*)&sVt[r0s * 72 + offs] = v0;
    *(uint4*)&sVt[r0s * 72 + offs + 8] = v1;
    __syncthreads();
    // prefetch next: K via idx loaded a full iteration earlier
    if (kbi + 1 < kend) {
      const u16* gk = Kg + (size_t)(rowbase + sNext2) * D_MODEL + colbase + offs;
      const u16* gv = gvb + (kbi + 1) * 64;
      k0 = *(const uint4*)gk;
      k1 = *(const uint4*)(gk + 8);
      v0 = *(const uint4*)gv;
      v1 = *(const uint4*)(gv + 8);
    }
    if (kbi + 2 < kend) sNext2 = idxb[(kbi + 2) * 64];

    // ---- S^T = K Q^T (+ pad mask on last partial block) ----
    const bool full = ((kbi + 1) << 6) <= cn;
    f32x4 st[2][4];
    __builtin_amdgcn_s_setprio(1);
#pragma unroll
    for (int tt = 0; tt < 4; ++tt) {
      bf16x8 ak0 = *(const bf16x8*)&sK[(tt * 16 + c) * 72 + qd * 8];
      bf16x8 ak1 = *(const bf16x8*)&sK[(tt * 16 + c) * 72 + qd * 8 + 32];
      f32x4 cin;
      if (full) {
        cin = f32x4{0.f, 0.f, 0.f, 0.f};
      } else {
        const int jb = (kbi << 6) + tt * 16 + qd * 4;
        cin = f32x4{jb + 0 < cn ? 0.f : MADD, jb + 1 < cn ? 0.f : MADD,
                    jb + 2 < cn ? 0.f : MADD, jb + 3 < cn ? 0.f : MADD};
      }
#pragma unroll
      for (int qt = 0; qt < 2; ++qt) {
        f32x4 a =
            __builtin_amdgcn_mfma_f32_16x16x32_bf16(ak0, aq[qt][0], cin, 0, 0, 0);
        a = __builtin_amdgcn_mfma_f32_16x16x32_bf16(ak1, aq[qt][1], a, 0, 0, 0);
        st[qt][tt] = a;
      }
    }
    __builtin_amdgcn_s_setprio(0);

    // ---- softmax numerator: p = exp2(s - MFIX) ----
#pragma unroll
    for (int qt = 0; qt < 2; ++qt) {
      float sum = 0.f;
      const int prow = (wq * 32 + qt * 16 + c) * 72;
#pragma unroll
      for (int tt = 0; tt < 4; ++tt) {
        u32 pk[2];
#pragma unroll
        for (int pr = 0; pr < 2; ++pr) {
          u32 p0 = __builtin_bit_cast(u32, fast_exp2(st[qt][tt][2 * pr] - MFIX));
          u32 p1 =
              __builtin_bit_cast(u32, fast_exp2(st[qt][tt][2 * pr + 1] - MFIX));
          u32 hi1 = p1 & 0xffff0000u;
          pk[pr] = (p0 >> 16) | hi1;
          sum += __builtin_bit_cast(float, p0 & 0xffff0000u);
          sum += __builtin_bit_cast(float, hi1);
        }
        uint2 pv2 = {pk[0], pk[1]};
        *(uint2*)&sP[prow + tt * 16 + qd * 4] = pv2;  // ds_write_b64
      }
      l[qt] += sum;
    }

    // ---- O^T += V^T P^T ----
    bf16x8 bp[2][2];
#pragma unroll
    for (int qt = 0; qt < 2; ++qt) {
      const int prow = (wq * 32 + qt * 16 + c) * 72;
      bp[qt][0] = *(const bf16x8*)&sP[prow + qd * 8];
      bp[qt][1] = *(const bf16x8*)&sP[prow + qd * 8 + 32];
    }
    __builtin_amdgcn_s_setprio(1);
#pragma unroll
    for (int dt = 0; dt < 4; ++dt) {
      bf16x8 av0 = *(const bf16x8*)&sVt[(dt * 16 + c) * 72 + qd * 8];
      bf16x8 av1 = *(const bf16x8*)&sVt[(dt * 16 + c) * 72 + qd * 8 + 32];
#pragma unroll
      for (int qt = 0; qt < 2; ++qt) {
        o[qt][dt] =
            __builtin_amdgcn_mfma_f32_16x16x32_bf16(av0, bp[qt][0], o[qt][dt], 0, 0, 0);
        o[qt][dt] =
            __builtin_amdgcn_mfma_f32_16x16x32_bf16(av1, bp[qt][1], o[qt][dt], 0, 0, 0);
      }
    }
    __builtin_amdgcn_s_setprio(0);
  }

  // ---- epilogue ----
  const size_t obase =
      (size_t)ck * 4194304 + ((size_t)((b * NHEAD + h) * SEQ) + qb * 128) * 64;
  const int mlbase = ((ck * 2 + b) * NHEAD + h) * SEQ + qb * 128;
#pragma unroll
  for (int qt = 0; qt < 2; ++qt) {
    float ls = l[qt];
    ls += __shfl_xor(ls, 16);
    ls += __shfl_xor(ls, 32);
    const float inv = (ls != 0.f) ? 1.0f / ls : 0.f;
    const int q = wq * 32 + qt * 16 + c;
#pragma unroll
    for (int dt = 0; dt < 4; ++dt) {
      u32 lo = (u32)f2bf(o[qt][dt][0] * inv) |
               ((u32)f2bf(o[qt][dt][1] * inv) << 16);
      u32 hi = (u32)f2bf(o[qt][dt][2] * inv) |
               ((u32)f2bf(o[qt][dt][3] * inv) << 16);
      uint2 ov = {lo, hi};
      *(uint2*)&Opart[obase + (size_t)q * 64 + dt * 16 + qd * 4] = ov;
    }
    if (qd == 0) ml[mlbase + q] = ls;
  }
}

// ---------------------------------------------------------------------------
// Kernel 5: combine the two key-chunk partials -> ctx bf16
// ---------------------------------------------------------------------------
__global__ __launch_bounds__(256) void mha_combine(
    const u16* __restrict__ Opart, const float* __restrict__ ml,
    u16* __restrict__ ctx) {
  const int tid = blockIdx.x * 256 + threadIdx.x;  // 524288 = 65536 rows x 8
  const int row = tid >> 3, d0 = (tid & 7) * 8;
  const int b = row >> 15, h = (row >> 11) & 15, q = row & 2047;
  float l1 = ml[row];
  float l2 = ml[65536 + row];
  float inv = 1.0f / (l1 + l2);
  float w1 = l1 * inv, w2 = l2 * inv;
  const size_t o1 = (size_t)row * 64 + d0;
  uint4 pa = *(const uint4*)(Opart + o1);
  uint4 pb = *(const uint4*)(Opart + 4194304 + o1);
  u32 wa[4] = {pa.x, pa.y, pa.z, pa.w};
  u32 wb[4] = {pb.x, pb.y, pb.z, pb.w};
  u32 out[4];
#pragma unroll
  for (int j = 0; j < 4; ++j) {
    float alo = __builtin_bit_cast(float, wa[j] << 16);
    float ahi = __builtin_bit_cast(float, wa[j] & 0xffff0000u);
    float blo = __builtin_bit_cast(float, wb[j] << 16);
    float bhi = __builtin_bit_cast(float, wb[j] & 0xffff0000u);
    float rlo = w1 * alo + w2 * blo;
    float rhi = w1 * ahi + w2 * bhi;
    out[j] = (u32)f2bf(rlo) | ((u32)f2bf(rhi) << 16);
  }
  uint4 ov = {out[0], out[1], out[2], out[3]};
  *(uint4*)&ctx[((size_t)(b * SEQ + q)) * D_MODEL + h * DK + d0] = ov;
}

// ---------------------------------------------------------------------------
// Kernel 6: output projection, fp32 out.  128x64 tile, BK=64, grid (32,16).
// TRIPLE-BUFFERED 2-DEEP COUNTED-VMCNT PIPELINE (pure gload16, zero staging
// registers).  Proven round 6.
// ---------------------------------------------------------------------------
__global__ __launch_bounds__(256) void gemm_out(
    const u16* __restrict__ A, const u16* __restrict__ Bw,
    const float* __restrict__ bias, float* __restrict__ Cout) {
  __shared__ __align__(16) u16 sAb[3][128 * 64];  // 48KB
  __shared__ __align__(16) u16 sBc[3][64 * 64];   // 24KB

  const int t = threadIdx.x;
  const int m0 = blockIdx.x * 128, n0 = blockIdx.y * 64;
  const int lane = t & 63, wv = t >> 6;
  const int wm = (wv >> 1) * 64, wn = (wv & 1) * 32;
  const int c = lane & 15, qd = lane >> 4;

  const int arow = t >> 3;
  const int aoff = (((t & 7) - arow) & 7) * 8;
  const u16* gaA = A + (size_t)(m0 + arow) * D_MODEL + aoff;
  const u16* gaB = Bw + (size_t)(n0 + arow) * D_MODEL + aoff;

  // ---- prologue: L(0):6, L(1):6 ----
#pragma unroll
  for (int j = 0; j < 4; ++j)
    gload16(gaA + (size_t)(32 * j) * D_MODEL, &sAb[0][(t + 256 * j) * 8]);
#pragma unroll
  for (int j = 0; j < 2; ++j)
    gload16(gaB + (size_t)(32 * j) * D_MODEL, &sBc[0][(t + 256 * j) * 8]);
  FENCE();
#pragma unroll
  for (int j = 0; j < 4; ++j)
    gload16(gaA + 64 + (size_t)(32 * j) * D_MODEL, &sAb[1][(t + 256 * j) * 8]);
#pragma unroll
  for (int j = 0; j < 2; ++j)
    gload16(gaB + 64 + (size_t)(32 * j) * D_MODEL, &sBc[1][(t + 256 * j) * 8]);
  FENCE();

  f32x4 acc[4][2] = {};

  for (int kbi = 0; kbi < 16; ++kbi) {
    const int cur = kbi % 3;
    // retire L(kbi):6; keep L(kbi+1):6 in flight (tail: drain)
    if (kbi == 15) { WVL(0); } else { WVL(6); }
    SBAR();
    if (kbi + 2 < 16) {
      const int nxt = (kbi + 2) % 3;
      const int kb2 = (kbi + 2) * 64;
#pragma unroll
      for (int j = 0; j < 4; ++j)
        gload16(gaA + kb2 + (size_t)(32 * j) * D_MODEL,
                &sAb[nxt][(t + 256 * j) * 8]);
#pragma unroll
      for (int j = 0; j < 2; ++j)
        gload16(gaB + kb2 + (size_t)(32 * j) * D_MODEL,
                &sBc[nxt][(t + 256 * j) * 8]);
      FENCE();
    }
    const u16* sA = sAb[cur];
    const u16* sB = sBc[cur];
#pragma unroll
    for (int s = 0; s < 2; ++s) {
      const int ao = ((s * 4 + qd + wm + c) & 7) * 8;
      const int bo = ((s * 4 + qd + wn + c) & 7) * 8;
      bf16x8 af[4], bfr[2];
#pragma unroll
      for (int i = 0; i < 4; ++i)
        af[i] = *(const bf16x8*)&sA[(wm + i * 16 + c) * 64 + ao];
#pragma unroll
      for (int j = 0; j < 2; ++j)
        bfr[j] = *(const bf16x8*)&sB[(wn + j * 16 + c) * 64 + bo];
#pragma unroll
      for (int i = 0; i < 4; ++i)
#pragma unroll
        for (int j = 0; j < 2; ++j)
          acc[i][j] = __builtin_amdgcn_mfma_f32_16x16x32_bf16(af[i], bfr[j],
                                                              acc[i][j], 0, 0, 0);
    }
  }

#pragma unroll
  for (int j = 0; j < 2; ++j) {
    const int col = n0 + wn + j * 16 + c;
    const float bv = bias[col];
#pragma unroll
    for (int i = 0; i < 4; ++i)
#pragma unroll
      for (int r = 0; r < 4; ++r) {
        const int row = m0 + wm + i * 16 + qd * 4 + r;
        Cout[(size_t)row * D_MODEL + col] = acc[i][j][r] + bv;
      }
  }
}

// ---------------------------------------------------------------------------
extern "C" void kernel_launch(void* const* d_in, const int* in_sizes, int n_in,
                              void* d_out, int out_size, void* d_ws,
                              size_t ws_size, hipStream_t stream) {
  const float* query = (const float*)d_in[0];
  const float* key   = (const float*)d_in[1];
  const float* value = (const float*)d_in[2];
  const int*   mask  = (const int*)d_in[3];
  const float* Wq = (const float*)d_in[4];
  const float* bq = (const float*)d_in[5];
  const float* Wk = (const float*)d_in[6];
  const float* bk = (const float*)d_in[7];
  const float* Wv = (const float*)d_in[8];
  const float* bv = (const float*)d_in[9];
  const float* Wo = (const float*)d_in[10];
  const float* bo = (const float*)d_in[11];

  // ws (u16 units, 32M = 64 MB):
  //   [0..4M)   VTc          [4M..12M)  Opart
  //   [12M..16M) Wb: Wq/Wk/Wv bf16 (dead after gemm_qkv; ml aliases Wq), Wo live
  //   [16M..28M) QKV: Q | K | VT(orig)   [28M..32M) CTX (idx/cnt alias early)
  u16* ws  = (u16*)d_ws;
  u16* Wb  = ws + ((size_t)12 << 20);
  u16* QKV = ws + ((size_t)16 << 20);
  u16* CTX = ws + ((size_t)28 << 20);
  u16* VTc = ws;
  u16* Opart = ws + ((size_t)4 << 20);
  float* ml = (float*)(ws + ((size_t)12 << 20));
  int* idxp = (int*)(ws + ((size_t)28 << 20));
  int* cntp = idxp + 2 * SEQ;

  mask_scan<<<dim3(2), dim3(256), 0, stream>>>(mask, idxp, cntp);
  w_convert<<<dim3(1024), dim3(256), 0, stream>>>(Wq, Wk, Wv, Wo, Wb);
  gemm_qkv<<<dim3(32, 8, 3), dim3(256), 0, stream>>>(query, key, value, Wb, bq,
                                                     bk, bv, QKV);
  vtc_gather<<<dim3(2048), dim3(256), 0, stream>>>(QKV + ((size_t)8 << 20), idxp,
                                                   cntp, VTc);
  mha_attn<<<dim3(16, 16, 4), dim3(256), 0, stream>>>(QKV, VTc, idxp, cntp,
                                                      Opart, ml);
  mha_combine<<<dim3(2048), dim3(256), 0, stream>>>(Opart, ml, CTX);
  gemm_out<<<dim3(32, 16), dim3(256), 0, stream>>>(CTX, Wb + ((size_t)3 << 20),
                                                   bo, (float*)d_out);
}

// Round 10
// 205.454 us; speedup vs baseline: 1.9932x; 1.0416x over previous
//
#include <hip/hip_runtime.h>
#include <cstdint>
#include <cstddef>

typedef unsigned short u16;
typedef unsigned int   u32;
typedef __bf16 bf16x8 __attribute__((ext_vector_type(8)));
typedef float  f32x4  __attribute__((ext_vector_type(4)));

#define D_MODEL 1024
#define SEQ     2048
#define NTOK    4096   // B*S
#define NHEAD   16
#define DK      64

// raw sync primitives for counted-vmcnt pipelines (no vmcnt(0) drains in-loop)
#define FENCE() asm volatile("" ::: "memory")
#define SBAR()  asm volatile("s_barrier" ::: "memory")
#define WVL(N)  asm volatile("s_waitcnt vmcnt(" #N ") lgkmcnt(0)" ::: "memory")

// hardware exp2 (v_exp_f32)
__device__ __forceinline__ float fast_exp2(float x) {
  return __builtin_amdgcn_exp2f(x);
}

// fp32 -> bf16 round-to-nearest-even (bit version, for memory-bound kernels)
__device__ __forceinline__ u16 f2bf(float f) {
  u32 u = __builtin_bit_cast(u32, f);
  u += 0x7fffu + ((u >> 16) & 1u);
  return (u16)(u >> 16);
}

// packed fp32x2 -> bf16x2 via compiler casts (lowers to v_cvt_pk_bf16_f32)
__device__ __forceinline__ u32 pkbf(float a, float b) {
  u16 x = __builtin_bit_cast(u16, (__bf16)a);
  u16 y = __builtin_bit_cast(u16, (__bf16)b);
  return (u32)x | ((u32)y << 16);
}

// async global->LDS, 16B per lane (dest must be wave-uniform base + lane*16)
__device__ __forceinline__ void gload16(const u16* g, u16* l) {
  __builtin_amdgcn_global_load_lds(
      (__attribute__((address_space(1))) void*)(uintptr_t)g,
      (__attribute__((address_space(3))) void*)l,
      16, 0, 0);
}

// ---------------------------------------------------------------------------
// Kernel 0+1 fused: blocks 0-1 run the per-batch mask compaction scan;
// blocks 2..1025 run the fp32->bf16 WEIGHT conversion (4 x 1M).
// (Independent outputs; fusion saves one kernel launch.)
// ---------------------------------------------------------------------------
__global__ __launch_bounds__(256) void scan_convert(
    const int* __restrict__ mask, int* __restrict__ idx, int* __restrict__ cnt,
    const float* __restrict__ wq, const float* __restrict__ wk,
    const float* __restrict__ wv, const float* __restrict__ wo,
    u16* __restrict__ wb) {
  __shared__ int sW[4];
  __shared__ int sTot;
  const int t = threadIdx.x;
  if (blockIdx.x < 2) {
    const int b = blockIdx.x;
    const int lane = t & 63, w = t >> 6;
    int m8[8];
    const int base = b * SEQ + t * 8;
    int tot = 0;
#pragma unroll
    for (int i = 0; i < 8; ++i) {
      m8[i] = (mask[base + i] != 0);
      tot += m8[i];
    }
    int v = tot;  // wave inclusive scan
#pragma unroll
    for (int d = 1; d < 64; d <<= 1) {
      int u = __shfl_up(v, d);
      if (lane >= d) v += u;
    }
    if (lane == 63) sW[w] = v;
    __syncthreads();
    if (t == 0) {
      int run = 0;
#pragma unroll
      for (int i = 0; i < 4; ++i) { int tmp = sW[i]; sW[i] = run; run += tmp; }
      sTot = run;
    }
    __syncthreads();
    int pos = v - tot + sW[w];  // exclusive prefix for this thread
#pragma unroll
    for (int i = 0; i < 8; ++i)
      if (m8[i]) idx[b * SEQ + pos++] = t * 8 + i;
    const int cn = sTot;
    if (t == 0) cnt[b] = cn;
    for (int j = cn + t; j < SEQ; j += 256) idx[b * SEQ + j] = 0;
  } else {
    const int total = 1 << 20;  // float4 chunks: 4 * 2^18
    for (int cid = (blockIdx.x - 2) * 256 + t; cid < total; cid += 1024 * 256) {
      int which = cid >> 18;
      int off = cid & ((1 << 18) - 1);
      const float* src =
          which == 0 ? wq : (which == 1 ? wk : (which == 2 ? wv : wo));
      u16* dst = wb + ((size_t)which << 20);
      float4 f = ((const float4*)src)[off];
      ushort4 u;
      u.x = f2bf(f.x); u.y = f2bf(f.y); u.z = f2bf(f.z); u.w = f2bf(f.w);
      ((ushort4*)dst)[off] = u;
    }
  }
}

// ---------------------------------------------------------------------------
// Kernel 2: QKV projections reading fp32 inputs DIRECTLY (conversion fused).
// C[M,N] = A[M,K]*B[N,K]^T + bias, bf16 out.  128x128 tile, BK=64.
// COUNTED-VMCNT PIPELINE (raw s_barrier, no vmcnt(0) drains in-loop):
//   B: gload16 -> sB dbuf, issued post-barrier, waited with vmcnt(8) a full
//      step later.  A: fp32 reg-staged "1.5-deep"; cvt_pk -> sA.
// FIFO: each step issues B(k+1):4 then A(k+2):8; loop-top WVL(8) retires
// B(k); post-MFMA WVL(4) retires A(k+1).  Rotated k-slots, conflict-free.
// VERIFIED 49.3us (rounds 4/6/8).  FAILED variants -- do not repeat:
//   r5 A-direct-fragment (coalescing loss, 106us); r7 128x64 @ (256,6)
//   (VGPR capped 40 -> 292MB spill); r9 single-sB 32KB (GPU fault, unisolated).
// z==0: Q scaled by 0.125*log2(e).  z==2: V transposed [b][h][d][s].
// ---------------------------------------------------------------------------
__global__ __launch_bounds__(256, 3) void gemm_qkv(
    const float* __restrict__ Aq, const float* __restrict__ Ak,
    const float* __restrict__ Av, const u16* __restrict__ Bw,
    const float* __restrict__ b0, const float* __restrict__ b1,
    const float* __restrict__ b2, u16* __restrict__ Cout) {
  __shared__ __align__(16) u16 smem[3 * 128 * 64];  // sA | sB0 | sB1; epi: sC
  u16* sA = smem;

  const int t = threadIdx.x;
  const int z = blockIdx.z;
  const float* Ap = (z == 0) ? Aq : ((z == 1) ? Ak : Av);
  const u16* Bp = Bw + ((size_t)z << 20);
  const float* bias = (z == 0) ? b0 : ((z == 1) ? b1 : b2);
  const float scl = (z == 0) ? 0.18033688011f : 1.0f;

  const int m0 = blockIdx.x * 128, n0 = blockIdx.y * 128;
  const int lane = t & 63, wv = t >> 6;
  const int wm = (wv >> 1) * 64, wn = (wv & 1) * 64;
  const int c = lane & 15, qd = lane >> 4;

  // staging: chunk cc = t + 256j -> row = cc>>3, phys slot t&7, source
  // k-slot rotated by row (32j = 0 mod 8 -> j-invariant)
  const int arow = t >> 3;
  const int aoff = (((t & 7) - arow) & 7) * 8;
  const float* gaA = Ap + (size_t)(m0 + arow) * D_MODEL + aoff;
  const u16* gaB = Bp + (size_t)(n0 + arow) * D_MODEL + aoff;

  float4 pa[4][2];
  u32 cv[4][4];

  // ---- prologue: issue A(0):8, B(0):4; convert A(0); issue A(1):8 ----
#pragma unroll
  for (int j = 0; j < 4; ++j) {
    pa[j][0] = *(const float4*)(gaA + (size_t)(32 * j) * D_MODEL);
    pa[j][1] = *(const float4*)(gaA + (size_t)(32 * j) * D_MODEL + 4);
  }
  FENCE();
#pragma unroll
  for (int j = 0; j < 4; ++j)
    gload16(gaB + (size_t)(32 * j) * D_MODEL, smem + 8192 + (t + 256 * j) * 8);
  WVL(4);  // A(0) arrived (B(0):4 outstanding)
#pragma unroll
  for (int j = 0; j < 4; ++j) {
    cv[j][0] = pkbf(pa[j][0].x, pa[j][0].y);
    cv[j][1] = pkbf(pa[j][0].z, pa[j][0].w);
    cv[j][2] = pkbf(pa[j][1].x, pa[j][1].y);
    cv[j][3] = pkbf(pa[j][1].z, pa[j][1].w);
  }
  FENCE();
#pragma unroll
  for (int j = 0; j < 4; ++j) {  // issue A(1):8
    pa[j][0] = *(const float4*)(gaA + 64 + (size_t)(32 * j) * D_MODEL);
    pa[j][1] = *(const float4*)(gaA + 64 + (size_t)(32 * j) * D_MODEL + 4);
  }
  FENCE();
#pragma unroll
  for (int j = 0; j < 4; ++j) {
    uint4 v4 = {cv[j][0], cv[j][1], cv[j][2], cv[j][3]};
    *(uint4*)&sA[(t + 256 * j) * 8] = v4;
  }

  f32x4 acc[4][4] = {};

#pragma unroll
  for (int kbi = 0; kbi < 16; ++kbi) {
    const int cur = kbi & 1;
    // loop-top: B(kbi) in LDS (retire it; keep A(kbi+1):8 in flight);
    // lgkmcnt(0) drains our sA ds_writes before the barrier.
    if (kbi == 15) { WVL(0); } else { WVL(8); }
    SBAR();
    // issue B(kbi+1) -> other sB buffer; flies across the whole step
    if (kbi + 1 < 16) {
      u16* sBn = smem + 8192 + (1 - cur) * 8192;
      const int kb2 = (kbi + 1) * 64;
#pragma unroll
      for (int j = 0; j < 4; ++j)
        gload16(gaB + kb2 + (size_t)(32 * j) * D_MODEL, sBn + (t + 256 * j) * 8);
    }
    FENCE();
    const u16* sB = smem + 8192 + cur * 8192;
#pragma unroll
    for (int s = 0; s < 2; ++s) {
      const int ao = ((s * 4 + qd + wm + c) & 7) * 8;  // rotated k-slot
      const int bo = ((s * 4 + qd + wn + c) & 7) * 8;
      bf16x8 af[4], bfr[4];
#pragma unroll
      for (int i = 0; i < 4; ++i)
        af[i] = *(const bf16x8*)&sA[(wm + i * 16 + c) * 64 + ao];
#pragma unroll
      for (int j = 0; j < 4; ++j)
        bfr[j] = *(const bf16x8*)&sB[(wn + j * 16 + c) * 64 + bo];
#pragma unroll
      for (int i = 0; i < 4; ++i)
#pragma unroll
        for (int j = 0; j < 4; ++j)
          acc[i][j] = __builtin_amdgcn_mfma_f32_16x16x32_bf16(af[i], bfr[j],
                                                              acc[i][j], 0, 0, 0);
    }
    if (kbi + 1 < 16) {
      WVL(4);  // A(kbi+1) regs arrived (B(kbi+1):4 outstanding)
#pragma unroll
      for (int j = 0; j < 4; ++j) {
        cv[j][0] = pkbf(pa[j][0].x, pa[j][0].y);
        cv[j][1] = pkbf(pa[j][0].z, pa[j][0].w);
        cv[j][2] = pkbf(pa[j][1].x, pa[j][1].y);
        cv[j][3] = pkbf(pa[j][1].z, pa[j][1].w);
      }
      if (kbi + 2 < 16) {  // issue A(kbi+2):8 into freed fp32 regs
        const int kb3 = (kbi + 2) * 64;
#pragma unroll
        for (int j = 0; j < 4; ++j) {
          pa[j][0] = *(const float4*)(gaA + kb3 + (size_t)(32 * j) * D_MODEL);
          pa[j][1] = *(const float4*)(gaA + kb3 + (size_t)(32 * j) * D_MODEL + 4);
        }
      }
      FENCE();
      SBAR();  // all waves done reading sA(kbi)
#pragma unroll
      for (int j = 0; j < 4; ++j) {
        uint4 v4 = {cv[j][0], cv[j][1], cv[j][2], cv[j][3]};
        *(uint4*)&sA[(t + 256 * j) * 8] = v4;
      }
    }
  }
  __syncthreads();  // full drain before smem reuse as sC

  u16* sC = smem;  // stride 136
  if (z == 2) {
#pragma unroll
    for (int j = 0; j < 4; ++j) {
      const int col = wn + j * 16 + c;
      const float bv = bias[n0 + col];
#pragma unroll
      for (int i = 0; i < 4; ++i)
#pragma unroll
        for (int r = 0; r < 4; ++r)
          sC[col * 136 + wm + i * 16 + qd * 4 + r] = f2bf(acc[i][j][r] + bv);
    }
    __syncthreads();
    u16* VT = Cout + ((size_t)2 << 22);
    const int bb = m0 >> 11, s0 = m0 & 2047;
    const int sidx = (t & 15) * 8;
#pragma unroll
    for (int outer = 0; outer < 8; ++outer) {
      const int vrow = outer * 16 + (t >> 4);
      const int col = n0 + vrow;
      const int hh = col >> 6, dd = col & 63;
      uint4 val = *(const uint4*)&sC[vrow * 136 + sidx];
      *(uint4*)&VT[((size_t)((bb * NHEAD + hh) * DK + dd)) * SEQ + s0 + sidx] =
          val;
    }
  } else {
#pragma unroll
    for (int j = 0; j < 4; ++j) {
      const int col = wn + j * 16 + c;
      const float bv = bias[n0 + col];
#pragma unroll
      for (int i = 0; i < 4; ++i)
#pragma unroll
        for (int r = 0; r < 4; ++r)
          sC[(wm + i * 16 + qd * 4 + r) * 136 + col] =
              f2bf((acc[i][j][r] + bv) * scl);
    }
    __syncthreads();
    u16* outp = Cout + ((size_t)z << 22);
    const int cidx = (t & 15) * 8;
#pragma unroll
    for (int outer = 0; outer < 8; ++outer) {
      const int lrow = outer * 16 + (t >> 4);
      uint4 val = *(const uint4*)&sC[lrow * 136 + cidx];
      *(uint4*)&outp[(size_t)(m0 + lrow) * D_MODEL + n0 + cidx] = val;
    }
  }
}

// ---------------------------------------------------------------------------
// Kernel 3: compact V^T along s: VTc[row][j] = VT[row][idx[b][j]], j<cnt[b].
// ---------------------------------------------------------------------------
__global__ __launch_bounds__(256) void vtc_gather(const u16* __restrict__ VT,
                                                  const int* __restrict__ idx,
                                                  const int* __restrict__ cnt,
                                                  u16* __restrict__ VTc) {
  const int row = blockIdx.x;  // (b*16+h)*64+d in [0,2048)
  const int b = row >> 10;
  const int cn = cnt[b];
  const u16* src = VT + (size_t)row * SEQ;
  u16* dst = VTc + (size_t)row * SEQ;
  const int* ib = idx + b * SEQ;
  for (int j = threadIdx.x; j < cn; j += 256) dst[j] = src[ib[j]];
}

// ---------------------------------------------------------------------------
// Kernel 4: flash attention over COMPACTED live keys.  S^T orientation,
// fixed-max softmax (m=16, exp2 domain).  Split-K x2, pipelined prefetch.
// (Round-6 verified form; setprio experiment r8 was neutral -> dropped.)
// ---------------------------------------------------------------------------
__global__ __launch_bounds__(256) void mha_attn(
    const u16* __restrict__ QKVb, const u16* __restrict__ VTc,
    const int* __restrict__ idx, const int* __restrict__ cnt,
    u16* __restrict__ Opart, float* __restrict__ ml) {
  __shared__ __align__(16) u16 sK[64 * 72];
  __shared__ __align__(16) u16 sVt[64 * 72];   // [d][key]
  __shared__ __align__(16) u16 sP[128 * 72];   // [q][key] = P^T rows

  const int t = threadIdx.x, lane = t & 63, wq = t >> 6;
  const int c = lane & 15, qd = lane >> 4;
  const int qb = blockIdx.x, h = blockIdx.y;
  const int b = blockIdx.z & 1, ck = blockIdx.z >> 1;

  const int cn = cnt[b];
  const int nb = (cn + 63) >> 6;
  const int half = (nb + 1) >> 1;
  const int kstart = ck ? half : 0;
  const int kend = ck ? nb : half;

  const u16* Qg = QKVb;
  const u16* Kg = QKVb + ((size_t)4 << 20);
  const u16* VTch = VTc + ((size_t)((b * NHEAD + h) * DK)) * SEQ;
  const int rowbase = b * SEQ;
  const int colbase = h * DK;

  // ---- Q B-fragments direct from global (lane n=q=c, k=qd*8+j) ----
  bf16x8 aq[2][2];
#pragma unroll
  for (int qt = 0; qt < 2; ++qt) {
    const u16* g = Qg +
                   (size_t)(rowbase + qb * 128 + wq * 32 + qt * 16 + c) * D_MODEL +
                   colbase + qd * 8;
    aq[qt][0] = *(const bf16x8*)g;
    aq[qt][1] = *(const bf16x8*)(g + 32);
  }

  float l[2] = {0.f, 0.f};
  f32x4 o[2][4] = {};
  const float MADD = -1.4426950e9f;  // NEG_INF * log2(e)
  const float MFIX = 16.0f;          // fixed softmax max (exp2 domain)

  const int r0s = t >> 2, offs = (t & 3) * 16;
  const u16* gvb = VTch + (size_t)r0s * SEQ + offs;
  const int* idxb = idx + b * SEQ + r0s;

  uint4 k0, k1, v0, v1;
  int sNext2 = 0;
  if (kstart < kend) {
    const int s0i = idxb[kstart * 64];
    const u16* gk = Kg + (size_t)(rowbase + s0i) * D_MODEL + colbase + offs;
    const u16* gv = gvb + kstart * 64;
    k0 = *(const uint4*)gk;
    k1 = *(const uint4*)(gk + 8);
    v0 = *(const uint4*)gv;
    v1 = *(const uint4*)(gv + 8);
    if (kstart + 1 < kend) sNext2 = idxb[(kstart + 1) * 64];
  }

  for (int kbi = kstart; kbi < kend; ++kbi) {
    __syncthreads();  // previous iteration's sK/sVt reads complete
    *(uint4*)&sK[r0s * 72 + offs] = k0;
    *(uint4*)&sK[r0s * 72 + offs + 8] = k1;
    *(uint4*)&sVt[r0s * 72 + offs] = v0;
    *(uint4*)&sVt[r0s * 72 + offs + 8] = v1;
    __syncthreads();
    // prefetch next: K via idx loaded a full iteration earlier
    if (kbi + 1 < kend) {
      const u16* gk = Kg + (size_t)(rowbase + sNext2) * D_MODEL + colbase + offs;
      const u16* gv = gvb + (kbi + 1) * 64;
      k0 = *(const uint4*)gk;
      k1 = *(const uint4*)(gk + 8);
      v0 = *(const uint4*)gv;
      v1 = *(const uint4*)(gv + 8);
    }
    if (kbi + 2 < kend) sNext2 = idxb[(kbi + 2) * 64];

    // ---- S^T = K Q^T (+ pad mask on last partial block) ----
    const bool full = ((kbi + 1) << 6) <= cn;
    f32x4 st[2][4];
#pragma unroll
    for (int tt = 0; tt < 4; ++tt) {
      bf16x8 ak0 = *(const bf16x8*)&sK[(tt * 16 + c) * 72 + qd * 8];
      bf16x8 ak1 = *(const bf16x8*)&sK[(tt * 16 + c) * 72 + qd * 8 + 32];
      f32x4 cin;
      if (full) {
        cin = f32x4{0.f, 0.f, 0.f, 0.f};
      } else {
        const int jb = (kbi << 6) + tt * 16 + qd * 4;
        cin = f32x4{jb + 0 < cn ? 0.f : MADD, jb + 1 < cn ? 0.f : MADD,
                    jb + 2 < cn ? 0.f : MADD, jb + 3 < cn ? 0.f : MADD};
      }
#pragma unroll
      for (int qt = 0; qt < 2; ++qt) {
        f32x4 a =
            __builtin_amdgcn_mfma_f32_16x16x32_bf16(ak0, aq[qt][0], cin, 0, 0, 0);
        a = __builtin_amdgcn_mfma_f32_16x16x32_bf16(ak1, aq[qt][1], a, 0, 0, 0);
        st[qt][tt] = a;
      }
    }

    // ---- softmax numerator: p = exp2(s - MFIX) ----
#pragma unroll
    for (int qt = 0; qt < 2; ++qt) {
      float sum = 0.f;
      const int prow = (wq * 32 + qt * 16 + c) * 72;
#pragma unroll
      for (int tt = 0; tt < 4; ++tt) {
        u32 pk[2];
#pragma unroll
        for (int pr = 0; pr < 2; ++pr) {
          u32 p0 = __builtin_bit_cast(u32, fast_exp2(st[qt][tt][2 * pr] - MFIX));
          u32 p1 =
              __builtin_bit_cast(u32, fast_exp2(st[qt][tt][2 * pr + 1] - MFIX));
          u32 hi1 = p1 & 0xffff0000u;
          pk[pr] = (p0 >> 16) | hi1;
          sum += __builtin_bit_cast(float, p0 & 0xffff0000u);
          sum += __builtin_bit_cast(float, hi1);
        }
        uint2 pv2 = {pk[0], pk[1]};
        *(uint2*)&sP[prow + tt * 16 + qd * 4] = pv2;  // ds_write_b64
      }
      l[qt] += sum;
    }

    // ---- O^T += V^T P^T ----
    bf16x8 bp[2][2];
#pragma unroll
    for (int qt = 0; qt < 2; ++qt) {
      const int prow = (wq * 32 + qt * 16 + c) * 72;
      bp[qt][0] = *(const bf16x8*)&sP[prow + qd * 8];
      bp[qt][1] = *(const bf16x8*)&sP[prow + qd * 8 + 32];
    }
#pragma unroll
    for (int dt = 0; dt < 4; ++dt) {
      bf16x8 av0 = *(const bf16x8*)&sVt[(dt * 16 + c) * 72 + qd * 8];
      bf16x8 av1 = *(const bf16x8*)&sVt[(dt * 16 + c) * 72 + qd * 8 + 32];
#pragma unroll
      for (int qt = 0; qt < 2; ++qt) {
        o[qt][dt] =
            __builtin_amdgcn_mfma_f32_16x16x32_bf16(av0, bp[qt][0], o[qt][dt], 0, 0, 0);
        o[qt][dt] =
            __builtin_amdgcn_mfma_f32_16x16x32_bf16(av1, bp[qt][1], o[qt][dt], 0, 0, 0);
      }
    }
  }

  // ---- epilogue ----
  const size_t obase =
      (size_t)ck * 4194304 + ((size_t)((b * NHEAD + h) * SEQ) + qb * 128) * 64;
  const int mlbase = ((ck * 2 + b) * NHEAD + h) * SEQ + qb * 128;
#pragma unroll
  for (int qt = 0; qt < 2; ++qt) {
    float ls = l[qt];
    ls += __shfl_xor(ls, 16);
    ls += __shfl_xor(ls, 32);
    const float inv = (ls != 0.f) ? 1.0f / ls : 0.f;
    const int q = wq * 32 + qt * 16 + c;
#pragma unroll
    for (int dt = 0; dt < 4; ++dt) {
      u32 lo = (u32)f2bf(o[qt][dt][0] * inv) |
               ((u32)f2bf(o[qt][dt][1] * inv) << 16);
      u32 hi = (u32)f2bf(o[qt][dt][2] * inv) |
               ((u32)f2bf(o[qt][dt][3] * inv) << 16);
      uint2 ov = {lo, hi};
      *(uint2*)&Opart[obase + (size_t)q * 64 + dt * 16 + qd * 4] = ov;
    }
    if (qd == 0) ml[mlbase + q] = ls;
  }
}

// ---------------------------------------------------------------------------
// Kernel 5: combine the two key-chunk partials -> ctx bf16
// ---------------------------------------------------------------------------
__global__ __launch_bounds__(256) void mha_combine(
    const u16* __restrict__ Opart, const float* __restrict__ ml,
    u16* __restrict__ ctx) {
  const int tid = blockIdx.x * 256 + threadIdx.x;  // 524288 = 65536 rows x 8
  const int row = tid >> 3, d0 = (tid & 7) * 8;
  const int b = row >> 15, h = (row >> 11) & 15, q = row & 2047;
  float l1 = ml[row];
  float l2 = ml[65536 + row];
  float inv = 1.0f / (l1 + l2);
  float w1 = l1 * inv, w2 = l2 * inv;
  const size_t o1 = (size_t)row * 64 + d0;
  uint4 pa = *(const uint4*)(Opart + o1);
  uint4 pb = *(const uint4*)(Opart + 4194304 + o1);
  u32 wa[4] = {pa.x, pa.y, pa.z, pa.w};
  u32 wb[4] = {pb.x, pb.y, pb.z, pb.w};
  u32 out[4];
#pragma unroll
  for (int j = 0; j < 4; ++j) {
    float alo = __builtin_bit_cast(float, wa[j] << 16);
    float ahi = __builtin_bit_cast(float, wa[j] & 0xffff0000u);
    float blo = __builtin_bit_cast(float, wb[j] << 16);
    float bhi = __builtin_bit_cast(float, wb[j] & 0xffff0000u);
    float rlo = w1 * alo + w2 * blo;
    float rhi = w1 * ahi + w2 * bhi;
    out[j] = (u32)f2bf(rlo) | ((u32)f2bf(rhi) << 16);
  }
  uint4 ov = {out[0], out[1], out[2], out[3]};
  *(uint4*)&ctx[((size_t)(b * SEQ + q)) * D_MODEL + h * DK + d0] = ov;
}

// ---------------------------------------------------------------------------
// Kernel 6: output projection, fp32 out.  128x64 tile, BK=64, grid (32,16).
// TRIPLE-BUFFERED 2-DEEP COUNTED-VMCNT PIPELINE (pure gload16, zero staging
// registers).  Proven round 6.
// ---------------------------------------------------------------------------
__global__ __launch_bounds__(256) void gemm_out(
    const u16* __restrict__ A, const u16* __restrict__ Bw,
    const float* __restrict__ bias, float* __restrict__ Cout) {
  __shared__ __align__(16) u16 sAb[3][128 * 64];  // 48KB
  __shared__ __align__(16) u16 sBc[3][64 * 64];   // 24KB

  const int t = threadIdx.x;
  const int m0 = blockIdx.x * 128, n0 = blockIdx.y * 64;
  const int lane = t & 63, wv = t >> 6;
  const int wm = (wv >> 1) * 64, wn = (wv & 1) * 32;
  const int c = lane & 15, qd = lane >> 4;

  const int arow = t >> 3;
  const int aoff = (((t & 7) - arow) & 7) * 8;
  const u16* gaA = A + (size_t)(m0 + arow) * D_MODEL + aoff;
  const u16* gaB = Bw + (size_t)(n0 + arow) * D_MODEL + aoff;

  // ---- prologue: L(0):6, L(1):6 ----
#pragma unroll
  for (int j = 0; j < 4; ++j)
    gload16(gaA + (size_t)(32 * j) * D_MODEL, &sAb[0][(t + 256 * j) * 8]);
#pragma unroll
  for (int j = 0; j < 2; ++j)
    gload16(gaB + (size_t)(32 * j) * D_MODEL, &sBc[0][(t + 256 * j) * 8]);
  FENCE();
#pragma unroll
  for (int j = 0; j < 4; ++j)
    gload16(gaA + 64 + (size_t)(32 * j) * D_MODEL, &sAb[1][(t + 256 * j) * 8]);
#pragma unroll
  for (int j = 0; j < 2; ++j)
    gload16(gaB + 64 + (size_t)(32 * j) * D_MODEL, &sBc[1][(t + 256 * j) * 8]);
  FENCE();

  f32x4 acc[4][2] = {};

  for (int kbi = 0; kbi < 16; ++kbi) {
    const int cur = kbi % 3;
    // retire L(kbi):6; keep L(kbi+1):6 in flight (tail: drain)
    if (kbi == 15) { WVL(0); } else { WVL(6); }
    SBAR();
    if (kbi + 2 < 16) {
      const int nxt = (kbi + 2) % 3;
      const int kb2 = (kbi + 2) * 64;
#pragma unroll
      for (int j = 0; j < 4; ++j)
        gload16(gaA + kb2 + (size_t)(32 * j) * D_MODEL,
                &sAb[nxt][(t + 256 * j) * 8]);
#pragma unroll
      for (int j = 0; j < 2; ++j)
        gload16(gaB + kb2 + (size_t)(32 * j) * D_MODEL,
                &sBc[nxt][(t + 256 * j) * 8]);
      FENCE();
    }
    const u16* sA = sAb[cur];
    const u16* sB = sBc[cur];
#pragma unroll
    for (int s = 0; s < 2; ++s) {
      const int ao = ((s * 4 + qd + wm + c) & 7) * 8;
      const int bo = ((s * 4 + qd + wn + c) & 7) * 8;
      bf16x8 af[4], bfr[2];
#pragma unroll
      for (int i = 0; i < 4; ++i)
        af[i] = *(const bf16x8*)&sA[(wm + i * 16 + c) * 64 + ao];
#pragma unroll
      for (int j = 0; j < 2; ++j)
        bfr[j] = *(const bf16x8*)&sB[(wn + j * 16 + c) * 64 + bo];
#pragma unroll
      for (int i = 0; i < 4; ++i)
#pragma unroll
        for (int j = 0; j < 2; ++j)
          acc[i][j] = __builtin_amdgcn_mfma_f32_16x16x32_bf16(af[i], bfr[j],
                                                              acc[i][j], 0, 0, 0);
    }
  }

#pragma unroll
  for (int j = 0; j < 2; ++j) {
    const int col = n0 + wn + j * 16 + c;
    const float bv = bias[col];
#pragma unroll
    for (int i = 0; i < 4; ++i)
#pragma unroll
      for (int r = 0; r < 4; ++r) {
        const int row = m0 + wm + i * 16 + qd * 4 + r;
        Cout[(size_t)row * D_MODEL + col] = acc[i][j][r] + bv;
      }
  }
}

// ---------------------------------------------------------------------------
extern "C" void kernel_launch(void* const* d_in, const int* in_sizes, int n_in,
                              void* d_out, int out_size, void* d_ws,
                              size_t ws_size, hipStream_t stream) {
  const float* query = (const float*)d_in[0];
  const float* key   = (const float*)d_in[1];
  const float* value = (const float*)d_in[2];
  const int*   mask  = (const int*)d_in[3];
  const float* Wq = (const float*)d_in[4];
  const float* bq = (const float*)d_in[5];
  const float* Wk = (const float*)d_in[6];
  const float* bk = (const float*)d_in[7];
  const float* Wv = (const float*)d_in[8];
  const float* bv = (const float*)d_in[9];
  const float* Wo = (const float*)d_in[10];
  const float* bo = (const float*)d_in[11];

  // ws (u16 units, 32M = 64 MB):
  //   [0..4M)   VTc          [4M..12M)  Opart
  //   [12M..16M) Wb: Wq/Wk/Wv bf16 (dead after gemm_qkv; ml aliases Wq), Wo live
  //   [16M..28M) QKV: Q | K | VT(orig)   [28M..32M) CTX (idx/cnt alias early)
  u16* ws  = (u16*)d_ws;
  u16* Wb  = ws + ((size_t)12 << 20);
  u16* QKV = ws + ((size_t)16 << 20);
  u16* CTX = ws + ((size_t)28 << 20);
  u16* VTc = ws;
  u16* Opart = ws + ((size_t)4 << 20);
  float* ml = (float*)(ws + ((size_t)12 << 20));
  int* idxp = (int*)(ws + ((size_t)28 << 20));
  int* cntp = idxp + 2 * SEQ;

  scan_convert<<<dim3(1026), dim3(256), 0, stream>>>(mask, idxp, cntp, Wq, Wk,
                                                     Wv, Wo, Wb);
  gemm_qkv<<<dim3(32, 8, 3), dim3(256), 0, stream>>>(query, key, value, Wb, bq,
                                                     bk, bv, QKV);
  vtc_gather<<<dim3(2048), dim3(256), 0, stream>>>(QKV + ((size_t)8 << 20), idxp,
                                                   cntp, VTc);
  mha_attn<<<dim3(16, 16, 4), dim3(256), 0, stream>>>(QKV, VTc, idxp, cntp,
                                                      Opart, ml);
  mha_combine<<<dim3(2048), dim3(256), 0, stream>>>(Opart, ml, CTX);
  gemm_out<<<dim3(32, 16), dim3(256), 0, stream>>>(CTX, Wb + ((size_t)3 << 20),
                                                   bo, (float*)d_out);
}